// Round 13
// baseline (1311.646 us; speedup 1.0000x reference)
//
#include <hip/hip_runtime.h>
#include <hip/hip_bf16.h>
#include <hip/hip_fp16.h>

#define T_TOKENS 4096
#define DIMC 1024
#define HID 4096
#define NE 8

typedef _Float16 f16;
typedef _Float16 f16x8 __attribute__((ext_vector_type(8)));
typedef _Float16 f16x4 __attribute__((ext_vector_type(4)));
typedef float f32x4 __attribute__((ext_vector_type(4)));

__device__ __forceinline__ void gload_lds16(const f16* g, f16* l) {
    __builtin_amdgcn_global_load_lds(
        (const __attribute__((address_space(1))) void*)g,
        (__attribute__((address_space(3))) void*)l, 16, 0, 0);
}

// ---------------------------------------------------------------------------
// Gating (fp32 exact) + bucket scatter + token->expert map.  [proven r12]
// ---------------------------------------------------------------------------
__global__ __launch_bounds__(256) void gating_kernel(
    const float* __restrict__ x, const float* __restrict__ gw,
    const float* __restrict__ gb, int* __restrict__ counts,
    int* __restrict__ list, int* __restrict__ eidx)
{
    const int wave = threadIdx.x >> 6;
    const int lane = threadIdx.x & 63;
    const int t = blockIdx.x * 4 + wave;

    const float* xr = x + (size_t)t * DIMC;
    float acc[NE];
#pragma unroll
    for (int e = 0; e < NE; ++e) acc[e] = 0.f;

    for (int i = 0; i < DIMC / 64; ++i) {
        const int k = i * 64 + lane;
        const float xv = xr[k];
        const float* g = gw + (size_t)k * NE;
#pragma unroll
        for (int e = 0; e < NE; ++e) acc[e] = fmaf(xv, g[e], acc[e]);
    }
#pragma unroll
    for (int off = 32; off >= 1; off >>= 1) {
#pragma unroll
        for (int e = 0; e < NE; ++e) acc[e] += __shfl_xor(acc[e], off, 64);
    }
    if (lane == 0) {
        float lg[NE];
#pragma unroll
        for (int e = 0; e < NE; ++e) lg[e] = acc[e] + gb[e];
        int i1 = 0; float v1 = lg[0];
#pragma unroll
        for (int e = 1; e < NE; ++e) { if (lg[e] > v1) { v1 = lg[e]; i1 = e; } }
        int i2 = -1; float v2 = -3.4e38f;
#pragma unroll
        for (int e = 0; e < NE; ++e) {
            if (e == i1) continue;
            if (lg[e] > v2) { v2 = lg[e]; i2 = e; }
        }
        const int es = (i1 > i2) ? i1 : i2;
        const int pos = atomicAdd(&counts[es], 1);
        list[es * T_TOKENS + pos] = t;
        eidx[t] = es;
    }
}

// ---------------------------------------------------------------------------
// x fp32 -> f16.  [proven r8]
// ---------------------------------------------------------------------------
__global__ __launch_bounds__(256) void xconvert(const float* __restrict__ x,
                                                f16* __restrict__ xh)
{
    const size_t i = ((size_t)blockIdx.x * 256 + threadIdx.x) * 8;
    const float4 a = *(const float4*)(x + i);
    const float4 b = *(const float4*)(x + i + 4);
    f16x8 v;
    v[0] = (f16)a.x; v[1] = (f16)a.y; v[2] = (f16)a.z; v[3] = (f16)a.w;
    v[4] = (f16)b.x; v[5] = (f16)b.y; v[6] = (f16)b.z; v[7] = (f16)b.w;
    *(f16x8*)(xh + i) = v;
}

// ---------------------------------------------------------------------------
// W [e][K][N] fp32 -> Wt [e][N][K] f16.  [proven r5/r8]
// ---------------------------------------------------------------------------
__global__ __launch_bounds__(256) void wconvert(const float* __restrict__ W,
                                                f16* __restrict__ Wt,
                                                int K, int N)
{
    __shared__ f16 Lt[64 * 72];
    const int n0 = blockIdx.x * 64;
    const int k0 = blockIdx.y * 64;
    const float* Ws = W + (size_t)blockIdx.z * K * N;
    const int t = threadIdx.x;

    const int no = (t & 15) * 4;
    const int kr = t >> 4;
#pragma unroll
    for (int p = 0; p < 4; ++p) {
        const int k = kr + p * 16;
        const float4 v = *(const float4*)(Ws + (size_t)(k0 + k) * N + n0 + no);
        Lt[(no + 0) * 72 + k] = (f16)v.x;
        Lt[(no + 1) * 72 + k] = (f16)v.y;
        Lt[(no + 2) * 72 + k] = (f16)v.z;
        Lt[(no + 3) * 72 + k] = (f16)v.w;
    }
    __syncthreads();
    const int n = t >> 2;
    const int ko = (t & 3) * 16;
    const f16x8 a = *(const f16x8*)&Lt[n * 72 + ko];
    const f16x8 b = *(const f16x8*)&Lt[n * 72 + ko + 8];
    f16* dst = Wt + ((size_t)blockIdx.z * N + n0 + n) * K + k0 + ko;
    *(f16x8*)(dst) = a;
    *(f16x8*)(dst + 8) = b;
}

// ---------------------------------------------------------------------------
// Grouped GEMM, 256x256 tile, 512 thr (8 waves 2m x 4n, per-wave 128x64 —
// fragment algebra lifted from refcheck-passed r11), r8-proven single-buffer
// 2-barrier loop, global_load_lds + involution swizzle, split-K:
// FIRST:  split-K=2 (z: e=z>>1, ks=z&1, 8 iters).  Bare f16 partial ->
//         Hp[ks][tok][gc]  (bias+gelu in gelu_combine).
// !FIRST: split-K=8 (z: e=z>>3, ks=z&7, 8 iters).  Bare f16 partial ->
//         p8[ks][tok][gc]  (2x + bias in reduce8).
// ---------------------------------------------------------------------------
template <bool FIRST>
__global__ __launch_bounds__(512, 4) void ffn_gemm8(
    const f16* __restrict__ A, const f16* __restrict__ Bt,
    const int* __restrict__ counts, const int* __restrict__ list,
    f16* __restrict__ Pout)
{
    constexpr int KB   = FIRST ? DIMC : HID;
    constexpr int NTOT = FIRST ? HID : DIMC;
    constexpr int KCH  = 512;                 // both: 8 K-iters per chunk
    constexpr int NKT  = 8;

    const int zz  = blockIdx.z;
    const int e   = FIRST ? (zz >> 1) : (zz >> 3);
    const int ks  = FIRST ? (zz & 1) : (zz & 7);
    const int kk0 = ks * KCH;
    const int m0  = blockIdx.y * 256;
    const int n0  = blockIdx.x * 256;
    const int cnt = counts[e];
    if (m0 >= cnt) return;

    __shared__ __align__(16) f16 As[256 * 64];   // 32 KB
    __shared__ __align__(16) f16 Bs[256 * 64];   // 32 KB
    __shared__ int rows[256];

    const int tid = threadIdx.x;
    if (tid < 256) rows[tid] = (m0 + tid < cnt) ? list[e * T_TOKENS + m0 + tid] : -1;
    __syncthreads();

    const int lane = tid & 63;
    const int wv   = tid >> 6;      // 0..7
    const int wr   = wv >> 2;       // 0..1  (128-row band)
    const int wc   = wv & 3;        // 0..3  (64-col band)

    // staging [proven r8 algebra]: wave wv covers rows wv*32+j*8+(lane>>3);
    // HW lane placement = base + lane*16B; source chunk = (lane&7)^(row&7).
    const f16* asrc[4];
    const f16* bsrc[4];
    f16* adst[4];
    f16* bdst[4];
#pragma unroll
    for (int j = 0; j < 4; ++j) {
        const int row   = wv * 32 + j * 8 + (lane >> 3);
        const int chunk = (lane & 7) ^ (row & 7);
        int tok = rows[row]; if (tok < 0) tok = 0;   // junk, epilogue skips
        asrc[j] = A + (size_t)tok * KB + kk0 + chunk * 8;
        bsrc[j] = Bt + ((size_t)e * NTOT + n0 + row) * KB + kk0 + chunk * 8;
        adst[j] = As + (wv * 32 + j * 8) * 64;
        bdst[j] = Bs + (wv * 32 + j * 8) * 64;
    }

    f32x4 acc[8][4];
#pragma unroll
    for (int mi = 0; mi < 8; ++mi)
#pragma unroll
        for (int ni = 0; ni < 4; ++ni) acc[mi][ni] = f32x4{0.f, 0.f, 0.f, 0.f};

    for (int kt = 0; kt < NKT; ++kt) {
        const int ko = kt * 64;
        __syncthreads();          // prior iter's fragment reads complete
#pragma unroll
        for (int j = 0; j < 4; ++j) {
            gload_lds16(asrc[j] + ko, adst[j]);
            gload_lds16(bsrc[j] + ko, bdst[j]);
        }
        __syncthreads();          // loads landed (compiler drains vmcnt)
#pragma unroll
        for (int kh = 0; kh < 2; ++kh) {
            f16x8 af[8], bf[4];
#pragma unroll
            for (int mi = 0; mi < 8; ++mi) {
                const int row = wr * 128 + mi * 16 + (lane & 15);
                const int kb  = (((lane >> 4) * 16) + kh * 64) ^ ((row & 7) << 4);
                af[mi] = *(const f16x8*)((const char*)As + row * 128 + kb);
            }
#pragma unroll
            for (int ni = 0; ni < 4; ++ni) {
                const int n  = wc * 64 + ni * 16 + (lane & 15);
                const int kb = (((lane >> 4) * 16) + kh * 64) ^ ((n & 7) << 4);
                bf[ni] = *(const f16x8*)((const char*)Bs + n * 128 + kb);
            }
#pragma unroll
            for (int mi = 0; mi < 8; ++mi)
#pragma unroll
                for (int ni = 0; ni < 4; ++ni)
                    acc[mi][ni] = __builtin_amdgcn_mfma_f32_16x16x32_f16(
                        af[mi], bf[ni], acc[mi][ni], 0, 0, 0);
        }
    }

    // ---- epilogue: bare f16 partial store (proven C/D mapping) ----
    constexpr int NOUT = FIRST ? HID : DIMC;
#pragma unroll
    for (int ni = 0; ni < 4; ++ni) {
        const int gc = n0 + wc * 64 + ni * 16 + (lane & 15);
#pragma unroll
        for (int mi = 0; mi < 8; ++mi) {
#pragma unroll
            for (int r = 0; r < 4; ++r) {
                const int lrow = wr * 128 + mi * 16 + (lane >> 4) * 4 + r;
                const int tok = rows[lrow];
                if (tok < 0) continue;
                Pout[((size_t)ks * T_TOKENS + tok) * NOUT + gc] =
                    (f16)acc[mi][ni][r];
            }
        }
    }
}

// ---------------------------------------------------------------------------
// H[t][c] = gelu(Hp0[t][c] + Hp1[t][c] + b1[eidx[t]][c])   [proven r12]
// ---------------------------------------------------------------------------
__global__ __launch_bounds__(256) void gelu_combine(
    const f16* __restrict__ Hp, const float* __restrict__ b1,
    const int* __restrict__ eidx, f16* __restrict__ H)
{
    const size_t i = ((size_t)blockIdx.x * 256 + threadIdx.x) * 8;
    const int t = (int)(i >> 12);          // / HID
    const int c = (int)(i & (HID - 1));
    const int e = eidx[t];
    const f16x8 a = *(const f16x8*)(Hp + i);
    const f16x8 b = *(const f16x8*)(Hp + (size_t)T_TOKENS * HID + i);
    const float4 ba = *(const float4*)(b1 + (size_t)e * HID + c);
    const float4 bb = *(const float4*)(b1 + (size_t)e * HID + c + 4);
    const float bj[8] = {ba.x, ba.y, ba.z, ba.w, bb.x, bb.y, bb.z, bb.w};
    f16x8 o;
#pragma unroll
    for (int j = 0; j < 8; ++j) {
        const float v = (float)a[j] + (float)b[j] + bj[j];
        o[j] = (f16)(0.5f * v * (1.f + erff(v * 0.70710678118f)));
    }
    *(f16x8*)(H + i) = o;
}

// ---------------------------------------------------------------------------
// out[t][c] = 2 * (sum_{ks<8} p8[ks][t][c]) + 2 * b2[eidx[t]][c]
// ---------------------------------------------------------------------------
__global__ __launch_bounds__(256) void reduce8(
    const f16* __restrict__ p8, const float* __restrict__ b2,
    const int* __restrict__ eidx, float* __restrict__ out)
{
    constexpr size_t SL = (size_t)T_TOKENS * DIMC;
    const size_t i = ((size_t)blockIdx.x * 256 + threadIdx.x) * 8;
    const int t = (int)(i >> 10);          // / DIMC
    const int c = (int)(i & (DIMC - 1));
    const int e = eidx[t];
    float s[8] = {0.f, 0.f, 0.f, 0.f, 0.f, 0.f, 0.f, 0.f};
#pragma unroll
    for (int ks = 0; ks < 8; ++ks) {
        const f16x8 v = *(const f16x8*)(p8 + (size_t)ks * SL + i);
#pragma unroll
        for (int j = 0; j < 8; ++j) s[j] += (float)v[j];
    }
    const float4 ba = *(const float4*)(b2 + (size_t)e * DIMC + c);
    const float4 bb = *(const float4*)(b2 + (size_t)e * DIMC + c + 4);
    const float bj[8] = {ba.x, ba.y, ba.z, ba.w, bb.x, bb.y, bb.z, bb.w};
    float4 o0, o1;
    o0.x = 2.f * (s[0] + bj[0]); o0.y = 2.f * (s[1] + bj[1]);
    o0.z = 2.f * (s[2] + bj[2]); o0.w = 2.f * (s[3] + bj[3]);
    o1.x = 2.f * (s[4] + bj[4]); o1.y = 2.f * (s[5] + bj[5]);
    o1.z = 2.f * (s[6] + bj[6]); o1.w = 2.f * (s[7] + bj[7]);
    *(float4*)(out + i) = o0;
    *(float4*)(out + i + 4) = o1;
}

// ===========================================================================
// FALLBACK (round-3, proven) — used when ws_size < 233MB.
// ===========================================================================
template <bool FIRST>
__global__ __launch_bounds__(256) void ffn_gemm_fb(
    const float* __restrict__ x, const f16* __restrict__ Hin,
    const float* __restrict__ w1, const float* __restrict__ b1,
    const float* __restrict__ w2, const float* __restrict__ b2,
    const int* __restrict__ counts, const int* __restrict__ list,
    f16* __restrict__ Hout, float* __restrict__ out)
{
    constexpr int K = FIRST ? DIMC : HID;
    constexpr int N = FIRST ? HID : DIMC;
    constexpr int LDT = 40;

    const int e  = blockIdx.z;
    const int m0 = blockIdx.y * 128;
    const int n0 = blockIdx.x * 128;
    const int cnt = counts[e];
    if (m0 >= cnt) return;

    __shared__ f16 Ab[128 * LDT];
    __shared__ f16 Bb[128 * LDT];
    __shared__ int rows[128];

    const int tid = threadIdx.x;
    if (tid < 128) {
        const int p = m0 + tid;
        rows[tid] = (p < cnt) ? list[e * T_TOKENS + p] : -1;
    }
    __syncthreads();

    const int lane = tid & 63;
    const int wv = tid >> 6;
    const int wr = wv >> 1, wc = wv & 1;

    f32x4 acc[4][4];
#pragma unroll
    for (int mi = 0; mi < 4; ++mi)
#pragma unroll
        for (int ni = 0; ni < 4; ++ni) acc[mi][ni] = f32x4{0.f, 0.f, 0.f, 0.f};

    const float* Bsrc = (FIRST ? w1 : w2) + (size_t)e * K * N;

    for (int kk = 0; kk < K; kk += 32) {
        __syncthreads();
        {
            const int r  = tid >> 3;
            const int ko = (tid & 7) * 4;
#pragma unroll
            for (int p = 0; p < 4; ++p) {
                const int row = p * 32 + r;
                const int tok = rows[row];
                f16x4 hv;
                if (FIRST) {
                    float4 v;
                    if (tok >= 0) v = *(const float4*)(x + (size_t)tok * K + kk + ko);
                    else          v = make_float4(0.f, 0.f, 0.f, 0.f);
                    hv[0] = (f16)v.x; hv[1] = (f16)v.y; hv[2] = (f16)v.z; hv[3] = (f16)v.w;
                } else {
                    if (tok >= 0) hv = *(const f16x4*)(Hin + (size_t)tok * K + kk + ko);
                    else { hv[0] = (f16)0.f; hv[1] = (f16)0.f; hv[2] = (f16)0.f; hv[3] = (f16)0.f; }
                }
                *(f16x4*)&Ab[row * LDT + ko] = hv;
            }
        }
        {
            const int kb = tid >> 5;
            const int no = (tid & 31) * 4;
#pragma unroll
            for (int p = 0; p < 4; ++p) {
                const int k = p * 8 + kb;
                const float4 v = *(const float4*)(Bsrc + (size_t)(kk + k) * N + n0 + no);
                f16 h[4];
                h[0] = (f16)v.x; h[1] = (f16)v.y; h[2] = (f16)v.z; h[3] = (f16)v.w;
#pragma unroll
                for (int i = 0; i < 4; ++i) {
                    const int n = no + i;
                    const int chunk = (k >> 3) ^ ((n >> 2) & 3);
                    Bb[n * LDT + chunk * 8 + (k & 7)] = h[i];
                }
            }
        }
        __syncthreads();
        f16x8 af[4], bf[4];
#pragma unroll
        for (int mi = 0; mi < 4; ++mi) {
            const int row = wr * 64 + mi * 16 + (lane & 15);
            af[mi] = *(const f16x8*)&Ab[row * LDT + (lane >> 4) * 8];
        }
#pragma unroll
        for (int ni = 0; ni < 4; ++ni) {
            const int n = wc * 64 + ni * 16 + (lane & 15);
            const int chunk = (lane >> 4) ^ ((n >> 2) & 3);
            bf[ni] = *(const f16x8*)&Bb[n * LDT + chunk * 8];
        }
#pragma unroll
        for (int mi = 0; mi < 4; ++mi)
#pragma unroll
            for (int ni = 0; ni < 4; ++ni)
                acc[mi][ni] = __builtin_amdgcn_mfma_f32_16x16x32_f16(
                    af[mi], bf[ni], acc[mi][ni], 0, 0, 0);
    }

#pragma unroll
    for (int ni = 0; ni < 4; ++ni) {
        const int gc = n0 + wc * 64 + ni * 16 + (lane & 15);
        const float bias = FIRST ? b1[(size_t)e * HID + gc]
                                 : b2[(size_t)e * DIMC + gc];
#pragma unroll
        for (int mi = 0; mi < 4; ++mi) {
#pragma unroll
            for (int r = 0; r < 4; ++r) {
                const int lrow = wr * 64 + mi * 16 + (lane >> 4) * 4 + r;
                const int tok = rows[lrow];
                if (tok < 0) continue;
                const float v = acc[mi][ni][r] + bias;
                if (FIRST) {
                    const float g = 0.5f * v * (1.f + erff(v * 0.70710678118f));
                    Hout[(size_t)tok * HID + gc] = (f16)g;
                } else {
                    out[(size_t)tok * DIMC + gc] = 2.f * v;
                }
            }
        }
    }
}

// ---------------------------------------------------------------------------
extern "C" void kernel_launch(void* const* d_in, const int* in_sizes, int n_in,
                              void* d_out, int out_size, void* d_ws, size_t ws_size,
                              hipStream_t stream)
{
    const float* x   = (const float*)d_in[0];
    const float* gw  = (const float*)d_in[1];
    const float* gb  = (const float*)d_in[2];
    const float* w1  = (const float*)d_in[3];
    const float* b1  = (const float*)d_in[4];
    const float* w2  = (const float*)d_in[5];
    const float* b2  = (const float*)d_in[6];
    float* out = (float*)d_out;

    const size_t MB = 1 << 20;
    // layout: counts@0(1KB), list@1KB(128KB), eidx@512KB(16KB),
    //         xh@1MB(8MB), H@9MB(32MB), w1t@41MB(64MB), w2t@105MB(64MB),
    //         Hp/p8@169MB(64MB) -> 233MB
    //         (Hp = f16[2][T][HID]; p8 = f16[8][T][DIMC]; same 64MB region)
    const size_t need_p = 233 * MB;

    if (ws_size >= need_p) {
        int* counts = (int*)d_ws;
        int* list   = (int*)((char*)d_ws + 1024);
        int* eidx   = (int*)((char*)d_ws + 512 * 1024);
        f16* xh     = (f16*)((char*)d_ws + 1 * MB);
        f16* H      = (f16*)((char*)d_ws + 9 * MB);
        f16* w1t    = (f16*)((char*)d_ws + 41 * MB);
        f16* w2t    = (f16*)((char*)d_ws + 105 * MB);
        f16* Hp     = (f16*)((char*)d_ws + 169 * MB);
        f16* p8     = (f16*)((char*)d_ws + 169 * MB);

        hipMemsetAsync(counts, 0, 1024, stream);

        gating_kernel<<<T_TOKENS / 4, 256, 0, stream>>>(x, gw, gb, counts, list, eidx);
        xconvert<<<(T_TOKENS * DIMC) / (256 * 8), 256, 0, stream>>>(x, xh);
        wconvert<<<dim3(HID / 64, DIMC / 64, NE), 256, 0, stream>>>(w1, w1t, DIMC, HID);
        wconvert<<<dim3(DIMC / 64, HID / 64, NE), 256, 0, stream>>>(w2, w2t, HID, DIMC);

        // GEMM1: 256^2, split-K=2, bare f16 partials
        ffn_gemm8<true><<<dim3(HID / 256, T_TOKENS / 256, NE * 2), 512, 0, stream>>>(
            xh, w1t, counts, list, Hp);
        // H = gelu(Hp0+Hp1+b1[e])
        gelu_combine<<<(T_TOKENS * HID) / (256 * 8), 256, 0, stream>>>(Hp, b1, eidx, H);
        // GEMM2: 256^2, split-K=8, bare f16 partials (overwrites Hp region)
        ffn_gemm8<false><<<dim3(DIMC / 256, T_TOKENS / 256, NE * 8), 512, 0, stream>>>(
            H, w2t, counts, list, p8);
        // out = 2*(sum p8) + 2*b2[e]
        reduce8<<<(T_TOKENS * DIMC) / (256 * 8), 256, 0, stream>>>(p8, b2, eidx, out);
        return;
    }

    // ---- fallback (round-3 path, needs 33MB) ----
    const size_t need_fb = (size_t)(1 << 18) + (size_t)T_TOKENS * HID * sizeof(f16);
    if (ws_size < need_fb) return;

    int* counts = (int*)d_ws;
    int* list   = (int*)((char*)d_ws + 1024);
    int* eidx   = (int*)((char*)d_ws + 160 * 1024);
    f16* H      = (f16*)((char*)d_ws + (1 << 18));

    hipMemsetAsync(d_ws, 0, 1024, stream);
    gating_kernel<<<T_TOKENS / 4, 256, 0, stream>>>(x, gw, gb, counts, list, eidx);
    ffn_gemm_fb<true><<<dim3(HID / 128, T_TOKENS / 128, NE), 256, 0, stream>>>(
        x, (const f16*)nullptr, w1, b1, w2, b2, counts, list, H, out);
    ffn_gemm_fb<false><<<dim3(DIMC / 128, T_TOKENS / 128, NE), 256, 0, stream>>>(
        x, (const f16*)H, w1, b1, w2, b2, counts, list, H, out);
}

// Round 14
// 418.836 us; speedup vs baseline: 3.1316x; 3.1316x over previous
//
#include <hip/hip_runtime.h>
#include <hip/hip_bf16.h>
#include <hip/hip_fp16.h>

#define T_TOKENS 4096
#define DIMC 1024
#define HID 4096
#define NE 8

typedef _Float16 f16;
typedef _Float16 f16x8 __attribute__((ext_vector_type(8)));
typedef _Float16 f16x4 __attribute__((ext_vector_type(4)));
typedef float f32x4 __attribute__((ext_vector_type(4)));

__device__ __forceinline__ void gload_lds16(const f16* g, f16* l) {
    __builtin_amdgcn_global_load_lds(
        (const __attribute__((address_space(1))) void*)g,
        (__attribute__((address_space(3))) void*)l, 16, 0, 0);
}

// ---------------------------------------------------------------------------
// Gating (fp32 exact) + bucket scatter + token->expert map.  [proven r12]
// ---------------------------------------------------------------------------
__global__ __launch_bounds__(256) void gating_kernel(
    const float* __restrict__ x, const float* __restrict__ gw,
    const float* __restrict__ gb, int* __restrict__ counts,
    int* __restrict__ list, int* __restrict__ eidx)
{
    const int wave = threadIdx.x >> 6;
    const int lane = threadIdx.x & 63;
    const int t = blockIdx.x * 4 + wave;

    const float* xr = x + (size_t)t * DIMC;
    float acc[NE];
#pragma unroll
    for (int e = 0; e < NE; ++e) acc[e] = 0.f;

    for (int i = 0; i < DIMC / 64; ++i) {
        const int k = i * 64 + lane;
        const float xv = xr[k];
        const float* g = gw + (size_t)k * NE;
#pragma unroll
        for (int e = 0; e < NE; ++e) acc[e] = fmaf(xv, g[e], acc[e]);
    }
#pragma unroll
    for (int off = 32; off >= 1; off >>= 1) {
#pragma unroll
        for (int e = 0; e < NE; ++e) acc[e] += __shfl_xor(acc[e], off, 64);
    }
    if (lane == 0) {
        float lg[NE];
#pragma unroll
        for (int e = 0; e < NE; ++e) lg[e] = acc[e] + gb[e];
        int i1 = 0; float v1 = lg[0];
#pragma unroll
        for (int e = 1; e < NE; ++e) { if (lg[e] > v1) { v1 = lg[e]; i1 = e; } }
        int i2 = -1; float v2 = -3.4e38f;
#pragma unroll
        for (int e = 0; e < NE; ++e) {
            if (e == i1) continue;
            if (lg[e] > v2) { v2 = lg[e]; i2 = e; }
        }
        const int es = (i1 > i2) ? i1 : i2;
        const int pos = atomicAdd(&counts[es], 1);
        list[es * T_TOKENS + pos] = t;
        eidx[t] = es;
    }
}

// ---------------------------------------------------------------------------
// x fp32 -> f16.  [proven r8]
// ---------------------------------------------------------------------------
__global__ __launch_bounds__(256) void xconvert(const float* __restrict__ x,
                                                f16* __restrict__ xh)
{
    const size_t i = ((size_t)blockIdx.x * 256 + threadIdx.x) * 8;
    const float4 a = *(const float4*)(x + i);
    const float4 b = *(const float4*)(x + i + 4);
    f16x8 v;
    v[0] = (f16)a.x; v[1] = (f16)a.y; v[2] = (f16)a.z; v[3] = (f16)a.w;
    v[4] = (f16)b.x; v[5] = (f16)b.y; v[6] = (f16)b.z; v[7] = (f16)b.w;
    *(f16x8*)(xh + i) = v;
}

// ---------------------------------------------------------------------------
// W [e][K][N] fp32 -> Wt [e][N][K] f16.  [proven r5/r8]
// ---------------------------------------------------------------------------
__global__ __launch_bounds__(256) void wconvert(const float* __restrict__ W,
                                                f16* __restrict__ Wt,
                                                int K, int N)
{
    __shared__ f16 Lt[64 * 72];
    const int n0 = blockIdx.x * 64;
    const int k0 = blockIdx.y * 64;
    const float* Ws = W + (size_t)blockIdx.z * K * N;
    const int t = threadIdx.x;

    const int no = (t & 15) * 4;
    const int kr = t >> 4;
#pragma unroll
    for (int p = 0; p < 4; ++p) {
        const int k = kr + p * 16;
        const float4 v = *(const float4*)(Ws + (size_t)(k0 + k) * N + n0 + no);
        Lt[(no + 0) * 72 + k] = (f16)v.x;
        Lt[(no + 1) * 72 + k] = (f16)v.y;
        Lt[(no + 2) * 72 + k] = (f16)v.z;
        Lt[(no + 3) * 72 + k] = (f16)v.w;
    }
    __syncthreads();
    const int n = t >> 2;
    const int ko = (t & 3) * 16;
    const f16x8 a = *(const f16x8*)&Lt[n * 72 + ko];
    const f16x8 b = *(const f16x8*)&Lt[n * 72 + ko + 8];
    f16* dst = Wt + ((size_t)blockIdx.z * N + n0 + n) * K + k0 + ko;
    *(f16x8*)(dst) = a;
    *(f16x8*)(dst + 8) = b;
}

// ---------------------------------------------------------------------------
// Grouped GEMM, 256x256 tile, 512 thr (8 waves 2m x 4n, per-wave 128x64),
// r8-proven single-buffer 2-barrier loop, global_load_lds + involution
// swizzle, split-K.  NOTE: default launch bounds — (512,4) in r13 meant
// 4 waves/EU -> 128-reg budget -> acc SPILLED to scratch (VGPR_Count=64,
// 673MB spill writes, 7x slowdown).  Default = 256-reg budget, no spill.
// FIRST:  split-K=2 (z: e=z>>1, ks=z&1, 8 iters) -> bare f16 Hp[ks].
// !FIRST: split-K=8 (z: e=z>>3, ks=z&7, 8 iters) -> bare f16 p8[ks].
// ---------------------------------------------------------------------------
template <bool FIRST>
__global__ __launch_bounds__(512) void ffn_gemm8(
    const f16* __restrict__ A, const f16* __restrict__ Bt,
    const int* __restrict__ counts, const int* __restrict__ list,
    f16* __restrict__ Pout)
{
    constexpr int KB   = FIRST ? DIMC : HID;
    constexpr int NTOT = FIRST ? HID : DIMC;
    constexpr int KCH  = 512;                 // both: 8 K-iters per chunk
    constexpr int NKT  = 8;

    const int zz  = blockIdx.z;
    const int e   = FIRST ? (zz >> 1) : (zz >> 3);
    const int ks  = FIRST ? (zz & 1) : (zz & 7);
    const int kk0 = ks * KCH;
    const int m0  = blockIdx.y * 256;
    const int n0  = blockIdx.x * 256;
    const int cnt = counts[e];
    if (m0 >= cnt) return;

    __shared__ __align__(16) f16 As[256 * 64];   // 32 KB
    __shared__ __align__(16) f16 Bs[256 * 64];   // 32 KB
    __shared__ int rows[256];

    const int tid = threadIdx.x;
    if (tid < 256) rows[tid] = (m0 + tid < cnt) ? list[e * T_TOKENS + m0 + tid] : -1;
    __syncthreads();

    const int lane = tid & 63;
    const int wv   = tid >> 6;      // 0..7
    const int wr   = wv >> 2;       // 0..1  (128-row band)
    const int wc   = wv & 3;        // 0..3  (64-col band)

    // staging [proven r8 algebra]: wave wv covers rows wv*32+j*8+(lane>>3);
    // HW lane placement = base + lane*16B; source chunk = (lane&7)^(row&7).
    const f16* asrc[4];
    const f16* bsrc[4];
    f16* adst[4];
    f16* bdst[4];
#pragma unroll
    for (int j = 0; j < 4; ++j) {
        const int row   = wv * 32 + j * 8 + (lane >> 3);
        const int chunk = (lane & 7) ^ (row & 7);
        int tok = rows[row]; if (tok < 0) tok = 0;   // junk, epilogue skips
        asrc[j] = A + (size_t)tok * KB + kk0 + chunk * 8;
        bsrc[j] = Bt + ((size_t)e * NTOT + n0 + row) * KB + kk0 + chunk * 8;
        adst[j] = As + (wv * 32 + j * 8) * 64;
        bdst[j] = Bs + (wv * 32 + j * 8) * 64;
    }

    f32x4 acc[8][4];
#pragma unroll
    for (int mi = 0; mi < 8; ++mi)
#pragma unroll
        for (int ni = 0; ni < 4; ++ni) acc[mi][ni] = f32x4{0.f, 0.f, 0.f, 0.f};

    for (int kt = 0; kt < NKT; ++kt) {
        const int ko = kt * 64;
        __syncthreads();          // prior iter's fragment reads complete
#pragma unroll
        for (int j = 0; j < 4; ++j) {
            gload_lds16(asrc[j] + ko, adst[j]);
            gload_lds16(bsrc[j] + ko, bdst[j]);
        }
        __syncthreads();          // loads landed (compiler drains vmcnt)
#pragma unroll
        for (int kh = 0; kh < 2; ++kh) {
            f16x8 af[8], bf[4];
#pragma unroll
            for (int mi = 0; mi < 8; ++mi) {
                const int row = wr * 128 + mi * 16 + (lane & 15);
                const int kb  = (((lane >> 4) * 16) + kh * 64) ^ ((row & 7) << 4);
                af[mi] = *(const f16x8*)((const char*)As + row * 128 + kb);
            }
#pragma unroll
            for (int ni = 0; ni < 4; ++ni) {
                const int n  = wc * 64 + ni * 16 + (lane & 15);
                const int kb = (((lane >> 4) * 16) + kh * 64) ^ ((n & 7) << 4);
                bf[ni] = *(const f16x8*)((const char*)Bs + n * 128 + kb);
            }
#pragma unroll
            for (int mi = 0; mi < 8; ++mi)
#pragma unroll
                for (int ni = 0; ni < 4; ++ni)
                    acc[mi][ni] = __builtin_amdgcn_mfma_f32_16x16x32_f16(
                        af[mi], bf[ni], acc[mi][ni], 0, 0, 0);
        }
    }

    // ---- epilogue: bare f16 partial store (proven C/D mapping) ----
    constexpr int NOUT = FIRST ? HID : DIMC;
#pragma unroll
    for (int ni = 0; ni < 4; ++ni) {
        const int gc = n0 + wc * 64 + ni * 16 + (lane & 15);
#pragma unroll
        for (int mi = 0; mi < 8; ++mi) {
#pragma unroll
            for (int r = 0; r < 4; ++r) {
                const int lrow = wr * 128 + mi * 16 + (lane >> 4) * 4 + r;
                const int tok = rows[lrow];
                if (tok < 0) continue;
                Pout[((size_t)ks * T_TOKENS + tok) * NOUT + gc] =
                    (f16)acc[mi][ni][r];
            }
        }
    }
}

// ---------------------------------------------------------------------------
// H[t][c] = gelu(Hp0[t][c] + Hp1[t][c] + b1[eidx[t]][c])   [proven r12]
// ---------------------------------------------------------------------------
__global__ __launch_bounds__(256) void gelu_combine(
    const f16* __restrict__ Hp, const float* __restrict__ b1,
    const int* __restrict__ eidx, f16* __restrict__ H)
{
    const size_t i = ((size_t)blockIdx.x * 256 + threadIdx.x) * 8;
    const int t = (int)(i >> 12);          // / HID
    const int c = (int)(i & (HID - 1));
    const int e = eidx[t];
    const f16x8 a = *(const f16x8*)(Hp + i);
    const f16x8 b = *(const f16x8*)(Hp + (size_t)T_TOKENS * HID + i);
    const float4 ba = *(const float4*)(b1 + (size_t)e * HID + c);
    const float4 bb = *(const float4*)(b1 + (size_t)e * HID + c + 4);
    const float bj[8] = {ba.x, ba.y, ba.z, ba.w, bb.x, bb.y, bb.z, bb.w};
    f16x8 o;
#pragma unroll
    for (int j = 0; j < 8; ++j) {
        const float v = (float)a[j] + (float)b[j] + bj[j];
        o[j] = (f16)(0.5f * v * (1.f + erff(v * 0.70710678118f)));
    }
    *(f16x8*)(H + i) = o;
}

// ---------------------------------------------------------------------------
// out[t][c] = 2 * (sum_{ks<8} p8[ks][t][c]) + 2 * b2[eidx[t]][c]  [proven r13]
// ---------------------------------------------------------------------------
__global__ __launch_bounds__(256) void reduce8(
    const f16* __restrict__ p8, const float* __restrict__ b2,
    const int* __restrict__ eidx, float* __restrict__ out)
{
    constexpr size_t SL = (size_t)T_TOKENS * DIMC;
    const size_t i = ((size_t)blockIdx.x * 256 + threadIdx.x) * 8;
    const int t = (int)(i >> 10);          // / DIMC
    const int c = (int)(i & (DIMC - 1));
    const int e = eidx[t];
    float s[8] = {0.f, 0.f, 0.f, 0.f, 0.f, 0.f, 0.f, 0.f};
#pragma unroll
    for (int ks = 0; ks < 8; ++ks) {
        const f16x8 v = *(const f16x8*)(p8 + (size_t)ks * SL + i);
#pragma unroll
        for (int j = 0; j < 8; ++j) s[j] += (float)v[j];
    }
    const float4 ba = *(const float4*)(b2 + (size_t)e * DIMC + c);
    const float4 bb = *(const float4*)(b2 + (size_t)e * DIMC + c + 4);
    const float bj[8] = {ba.x, ba.y, ba.z, ba.w, bb.x, bb.y, bb.z, bb.w};
    float4 o0, o1;
    o0.x = 2.f * (s[0] + bj[0]); o0.y = 2.f * (s[1] + bj[1]);
    o0.z = 2.f * (s[2] + bj[2]); o0.w = 2.f * (s[3] + bj[3]);
    o1.x = 2.f * (s[4] + bj[4]); o1.y = 2.f * (s[5] + bj[5]);
    o1.z = 2.f * (s[6] + bj[6]); o1.w = 2.f * (s[7] + bj[7]);
    *(float4*)(out + i) = o0;
    *(float4*)(out + i + 4) = o1;
}

// ===========================================================================
// FALLBACK (round-3, proven) — used when ws_size < 233MB.
// ===========================================================================
template <bool FIRST>
__global__ __launch_bounds__(256) void ffn_gemm_fb(
    const float* __restrict__ x, const f16* __restrict__ Hin,
    const float* __restrict__ w1, const float* __restrict__ b1,
    const float* __restrict__ w2, const float* __restrict__ b2,
    const int* __restrict__ counts, const int* __restrict__ list,
    f16* __restrict__ Hout, float* __restrict__ out)
{
    constexpr int K = FIRST ? DIMC : HID;
    constexpr int N = FIRST ? HID : DIMC;
    constexpr int LDT = 40;

    const int e  = blockIdx.z;
    const int m0 = blockIdx.y * 128;
    const int n0 = blockIdx.x * 128;
    const int cnt = counts[e];
    if (m0 >= cnt) return;

    __shared__ f16 Ab[128 * LDT];
    __shared__ f16 Bb[128 * LDT];
    __shared__ int rows[128];

    const int tid = threadIdx.x;
    if (tid < 128) {
        const int p = m0 + tid;
        rows[tid] = (p < cnt) ? list[e * T_TOKENS + p] : -1;
    }
    __syncthreads();

    const int lane = tid & 63;
    const int wv = tid >> 6;
    const int wr = wv >> 1, wc = wv & 1;

    f32x4 acc[4][4];
#pragma unroll
    for (int mi = 0; mi < 4; ++mi)
#pragma unroll
        for (int ni = 0; ni < 4; ++ni) acc[mi][ni] = f32x4{0.f, 0.f, 0.f, 0.f};

    const float* Bsrc = (FIRST ? w1 : w2) + (size_t)e * K * N;

    for (int kk = 0; kk < K; kk += 32) {
        __syncthreads();
        {
            const int r  = tid >> 3;
            const int ko = (tid & 7) * 4;
#pragma unroll
            for (int p = 0; p < 4; ++p) {
                const int row = p * 32 + r;
                const int tok = rows[row];
                f16x4 hv;
                if (FIRST) {
                    float4 v;
                    if (tok >= 0) v = *(const float4*)(x + (size_t)tok * K + kk + ko);
                    else          v = make_float4(0.f, 0.f, 0.f, 0.f);
                    hv[0] = (f16)v.x; hv[1] = (f16)v.y; hv[2] = (f16)v.z; hv[3] = (f16)v.w;
                } else {
                    if (tok >= 0) hv = *(const f16x4*)(Hin + (size_t)tok * K + kk + ko);
                    else { hv[0] = (f16)0.f; hv[1] = (f16)0.f; hv[2] = (f16)0.f; hv[3] = (f16)0.f; }
                }
                *(f16x4*)&Ab[row * LDT + ko] = hv;
            }
        }
        {
            const int kb = tid >> 5;
            const int no = (tid & 31) * 4;
#pragma unroll
            for (int p = 0; p < 4; ++p) {
                const int k = p * 8 + kb;
                const float4 v = *(const float4*)(Bsrc + (size_t)(kk + k) * N + n0 + no);
                f16 h[4];
                h[0] = (f16)v.x; h[1] = (f16)v.y; h[2] = (f16)v.z; h[3] = (f16)v.w;
#pragma unroll
                for (int i = 0; i < 4; ++i) {
                    const int n = no + i;
                    const int chunk = (k >> 3) ^ ((n >> 2) & 3);
                    Bb[n * LDT + chunk * 8 + (k & 7)] = h[i];
                }
            }
        }
        __syncthreads();
        f16x8 af[4], bf[4];
#pragma unroll
        for (int mi = 0; mi < 4; ++mi) {
            const int row = wr * 64 + mi * 16 + (lane & 15);
            af[mi] = *(const f16x8*)&Ab[row * LDT + (lane >> 4) * 8];
        }
#pragma unroll
        for (int ni = 0; ni < 4; ++ni) {
            const int n = wc * 64 + ni * 16 + (lane & 15);
            const int chunk = (lane >> 4) ^ ((n >> 2) & 3);
            bf[ni] = *(const f16x8*)&Bb[n * LDT + chunk * 8];
        }
#pragma unroll
        for (int mi = 0; mi < 4; ++mi)
#pragma unroll
            for (int ni = 0; ni < 4; ++ni)
                acc[mi][ni] = __builtin_amdgcn_mfma_f32_16x16x32_f16(
                    af[mi], bf[ni], acc[mi][ni], 0, 0, 0);
    }

#pragma unroll
    for (int ni = 0; ni < 4; ++ni) {
        const int gc = n0 + wc * 64 + ni * 16 + (lane & 15);
        const float bias = FIRST ? b1[(size_t)e * HID + gc]
                                 : b2[(size_t)e * DIMC + gc];
#pragma unroll
        for (int mi = 0; mi < 4; ++mi) {
#pragma unroll
            for (int r = 0; r < 4; ++r) {
                const int lrow = wr * 64 + mi * 16 + (lane >> 4) * 4 + r;
                const int tok = rows[lrow];
                if (tok < 0) continue;
                const float v = acc[mi][ni][r] + bias;
                if (FIRST) {
                    const float g = 0.5f * v * (1.f + erff(v * 0.70710678118f));
                    Hout[(size_t)tok * HID + gc] = (f16)g;
                } else {
                    out[(size_t)tok * DIMC + gc] = 2.f * v;
                }
            }
        }
    }
}

// ---------------------------------------------------------------------------
extern "C" void kernel_launch(void* const* d_in, const int* in_sizes, int n_in,
                              void* d_out, int out_size, void* d_ws, size_t ws_size,
                              hipStream_t stream)
{
    const float* x   = (const float*)d_in[0];
    const float* gw  = (const float*)d_in[1];
    const float* gb  = (const float*)d_in[2];
    const float* w1  = (const float*)d_in[3];
    const float* b1  = (const float*)d_in[4];
    const float* w2  = (const float*)d_in[5];
    const float* b2  = (const float*)d_in[6];
    float* out = (float*)d_out;

    const size_t MB = 1 << 20;
    // layout: counts@0(1KB), list@1KB(128KB), eidx@512KB(16KB),
    //         xh@1MB(8MB), H@9MB(32MB), w1t@41MB(64MB), w2t@105MB(64MB),
    //         Hp/p8@169MB(64MB) -> 233MB
    const size_t need_p = 233 * MB;

    if (ws_size >= need_p) {
        int* counts = (int*)d_ws;
        int* list   = (int*)((char*)d_ws + 1024);
        int* eidx   = (int*)((char*)d_ws + 512 * 1024);
        f16* xh     = (f16*)((char*)d_ws + 1 * MB);
        f16* H      = (f16*)((char*)d_ws + 9 * MB);
        f16* w1t    = (f16*)((char*)d_ws + 41 * MB);
        f16* w2t    = (f16*)((char*)d_ws + 105 * MB);
        f16* Hp     = (f16*)((char*)d_ws + 169 * MB);
        f16* p8     = (f16*)((char*)d_ws + 169 * MB);

        hipMemsetAsync(counts, 0, 1024, stream);

        gating_kernel<<<T_TOKENS / 4, 256, 0, stream>>>(x, gw, gb, counts, list, eidx);
        xconvert<<<(T_TOKENS * DIMC) / (256 * 8), 256, 0, stream>>>(x, xh);
        wconvert<<<dim3(HID / 64, DIMC / 64, NE), 256, 0, stream>>>(w1, w1t, DIMC, HID);
        wconvert<<<dim3(DIMC / 64, HID / 64, NE), 256, 0, stream>>>(w2, w2t, HID, DIMC);

        // GEMM1: 256^2, split-K=2, bare f16 partials
        ffn_gemm8<true><<<dim3(HID / 256, T_TOKENS / 256, NE * 2), 512, 0, stream>>>(
            xh, w1t, counts, list, Hp);
        // H = gelu(Hp0+Hp1+b1[e])
        gelu_combine<<<(T_TOKENS * HID) / (256 * 8), 256, 0, stream>>>(Hp, b1, eidx, H);
        // GEMM2: 256^2, split-K=8, bare f16 partials (overwrites Hp region)
        ffn_gemm8<false><<<dim3(DIMC / 256, T_TOKENS / 256, NE * 8), 512, 0, stream>>>(
            H, w2t, counts, list, p8);
        // out = 2*(sum p8) + 2*b2[e]
        reduce8<<<(T_TOKENS * DIMC) / (256 * 8), 256, 0, stream>>>(p8, b2, eidx, out);
        return;
    }

    // ---- fallback (round-3 path, needs 33MB) ----
    const size_t need_fb = (size_t)(1 << 18) + (size_t)T_TOKENS * HID * sizeof(f16);
    if (ws_size < need_fb) return;

    int* counts = (int*)d_ws;
    int* list   = (int*)((char*)d_ws + 1024);
    int* eidx   = (int*)((char*)d_ws + 160 * 1024);
    f16* H      = (f16*)((char*)d_ws + (1 << 18));

    hipMemsetAsync(d_ws, 0, 1024, stream);
    gating_kernel<<<T_TOKENS / 4, 256, 0, stream>>>(x, gw, gb, counts, list, eidx);
    ffn_gemm_fb<true><<<dim3(HID / 128, T_TOKENS / 128, NE), 256, 0, stream>>>(
        x, (const f16*)nullptr, w1, b1, w2, b2, counts, list, H, out);
    ffn_gemm_fb<false><<<dim3(DIMC / 128, T_TOKENS / 128, NE), 256, 0, stream>>>(
        x, (const f16*)H, w1, b1, w2, b2, counts, list, H, out);
}

// Round 15
// 341.437 us; speedup vs baseline: 3.8415x; 1.2267x over previous
//
#include <hip/hip_runtime.h>
#include <hip/hip_bf16.h>
#include <hip/hip_fp16.h>

#define T_TOKENS 4096
#define DIMC 1024
#define HID 4096
#define NE 8

typedef _Float16 f16;
typedef _Float16 f16x8 __attribute__((ext_vector_type(8)));
typedef _Float16 f16x4 __attribute__((ext_vector_type(4)));
typedef float f32x4 __attribute__((ext_vector_type(4)));

__device__ __forceinline__ void gload_lds16(const f16* g, f16* l) {
    __builtin_amdgcn_global_load_lds(
        (const __attribute__((address_space(1))) void*)g,
        (__attribute__((address_space(3))) void*)l, 16, 0, 0);
}

// ---------------------------------------------------------------------------
// Gating (fp32 exact) + bucket scatter + token->expert map.  [proven r12]
// ---------------------------------------------------------------------------
__global__ __launch_bounds__(256) void gating_kernel(
    const float* __restrict__ x, const float* __restrict__ gw,
    const float* __restrict__ gb, int* __restrict__ counts,
    int* __restrict__ list, int* __restrict__ eidx)
{
    const int wave = threadIdx.x >> 6;
    const int lane = threadIdx.x & 63;
    const int t = blockIdx.x * 4 + wave;

    const float* xr = x + (size_t)t * DIMC;
    float acc[NE];
#pragma unroll
    for (int e = 0; e < NE; ++e) acc[e] = 0.f;

    for (int i = 0; i < DIMC / 64; ++i) {
        const int k = i * 64 + lane;
        const float xv = xr[k];
        const float* g = gw + (size_t)k * NE;
#pragma unroll
        for (int e = 0; e < NE; ++e) acc[e] = fmaf(xv, g[e], acc[e]);
    }
#pragma unroll
    for (int off = 32; off >= 1; off >>= 1) {
#pragma unroll
        for (int e = 0; e < NE; ++e) acc[e] += __shfl_xor(acc[e], off, 64);
    }
    if (lane == 0) {
        float lg[NE];
#pragma unroll
        for (int e = 0; e < NE; ++e) lg[e] = acc[e] + gb[e];
        int i1 = 0; float v1 = lg[0];
#pragma unroll
        for (int e = 1; e < NE; ++e) { if (lg[e] > v1) { v1 = lg[e]; i1 = e; } }
        int i2 = -1; float v2 = -3.4e38f;
#pragma unroll
        for (int e = 0; e < NE; ++e) {
            if (e == i1) continue;
            if (lg[e] > v2) { v2 = lg[e]; i2 = e; }
        }
        const int es = (i1 > i2) ? i1 : i2;
        const int pos = atomicAdd(&counts[es], 1);
        list[es * T_TOKENS + pos] = t;
        eidx[t] = es;
    }
}

// ---------------------------------------------------------------------------
// x fp32 -> f16.  [proven r8]
// ---------------------------------------------------------------------------
__global__ __launch_bounds__(256) void xconvert(const float* __restrict__ x,
                                                f16* __restrict__ xh)
{
    const size_t i = ((size_t)blockIdx.x * 256 + threadIdx.x) * 8;
    const float4 a = *(const float4*)(x + i);
    const float4 b = *(const float4*)(x + i + 4);
    f16x8 v;
    v[0] = (f16)a.x; v[1] = (f16)a.y; v[2] = (f16)a.z; v[3] = (f16)a.w;
    v[4] = (f16)b.x; v[5] = (f16)b.y; v[6] = (f16)b.z; v[7] = (f16)b.w;
    *(f16x8*)(xh + i) = v;
}

// ---------------------------------------------------------------------------
// W [e][K][N] fp32 -> Wt [e][N][K] f16.  [proven r5/r8]
// ---------------------------------------------------------------------------
__global__ __launch_bounds__(256) void wconvert(const float* __restrict__ W,
                                                f16* __restrict__ Wt,
                                                int K, int N)
{
    __shared__ f16 Lt[64 * 72];
    const int n0 = blockIdx.x * 64;
    const int k0 = blockIdx.y * 64;
    const float* Ws = W + (size_t)blockIdx.z * K * N;
    const int t = threadIdx.x;

    const int no = (t & 15) * 4;
    const int kr = t >> 4;
#pragma unroll
    for (int p = 0; p < 4; ++p) {
        const int k = kr + p * 16;
        const float4 v = *(const float4*)(Ws + (size_t)(k0 + k) * N + n0 + no);
        Lt[(no + 0) * 72 + k] = (f16)v.x;
        Lt[(no + 1) * 72 + k] = (f16)v.y;
        Lt[(no + 2) * 72 + k] = (f16)v.z;
        Lt[(no + 3) * 72 + k] = (f16)v.w;
    }
    __syncthreads();
    const int n = t >> 2;
    const int ko = (t & 3) * 16;
    const f16x8 a = *(const f16x8*)&Lt[n * 72 + ko];
    const f16x8 b = *(const f16x8*)&Lt[n * 72 + ko + 8];
    f16* dst = Wt + ((size_t)blockIdx.z * N + n0 + n) * K + k0 + ko;
    *(f16x8*)(dst) = a;
    *(f16x8*)(dst + 8) = b;
}

// ---------------------------------------------------------------------------
// Grouped GEMM, 128m x 256n tile, BK=32, 512 thr (8 waves 2m x 4n, per-wave
// 64x64 = r8-verbatim acc[4][4] fragments).  24.5 KB LDS -> 4 blocks/CU
// (32-wave cap), 1024 useful blocks = fully co-resident.  r8-proven
// 2-barrier single-buffer loop + global_load_lds.
// BK=32 involution swizzle: 4 chunks/row, f(r)=((r>>2)^r)&3; source chunk
// = slot^f(row) on stage, read slot = chunk^f(row) -> 16-lane fragment read
// spreads over 8 distinct 16B slots = conflict-free (2 lanes/bank).
// FIRST:  KB=1024, N=4096 (16 n-tiles), sk=2 -> bare f16 Hp[ks].
// !FIRST: KB=4096, N=1024 (4 n-tiles),  sk=8 -> bare f16 p8[ks].
// Both: KCH=512, NKT=16.
// ---------------------------------------------------------------------------
template <bool FIRST>
__global__ __launch_bounds__(512) void ffn_gemm9(
    const f16* __restrict__ A, const f16* __restrict__ Bt,
    const int* __restrict__ counts, const int* __restrict__ list,
    f16* __restrict__ Pout)
{
    constexpr int KB   = FIRST ? DIMC : HID;
    constexpr int NTOT = FIRST ? HID : DIMC;
    constexpr int NKT  = 16;

    const int zz  = blockIdx.z;
    const int e   = FIRST ? (zz >> 1) : (zz >> 3);
    const int ks  = FIRST ? (zz & 1) : (zz & 7);
    const int kk0 = ks * 512;
    const int m0  = blockIdx.y * 128;
    const int n0  = blockIdx.x * 256;
    const int cnt = counts[e];
    if (m0 >= cnt) return;

    __shared__ __align__(16) f16 As[128 * 32];   // 8 KB
    __shared__ __align__(16) f16 Bs[256 * 32];   // 16 KB
    __shared__ int rows[128];

    const int tid = threadIdx.x;
    if (tid < 128) rows[tid] = (m0 + tid < cnt) ? list[e * T_TOKENS + m0 + tid] : -1;
    __syncthreads();

    const int lane = tid & 63;
    const int wv   = tid >> 6;      // 0..7
    const int wr   = wv >> 2;       // 0..1  (64-row band of 128)
    const int wc   = wv & 3;        // 0..3  (64-col band of 256)

    // staging: 16 rows per wave-instr (lane>>2), 4 chunks of 16B (lane&3).
    // source chunk = (lane&3) ^ f(row), f(r) = ((r>>2)^r)&3.
    const int lrow4 = lane >> 2;
    const int lslot = lane & 3;

    // A: 128 rows = 1 instr/thread (wave rows wv*16 + lrow4)
    const int arow = wv * 16 + lrow4;
    int tokA = rows[arow]; if (tokA < 0) tokA = 0;   // junk, epilogue skips
    const int achunk = lslot ^ (((arow >> 2) ^ arow) & 3);
    const f16* asrc = A + (size_t)tokA * KB + kk0 + achunk * 8;
    f16* adst = As + (wv * 16) * 32;                 // wave-uniform

    // B: 256 rows = 2 instr/thread (wave rows wv*32 + j*16 + lrow4)
    const f16* bsrc[2];
    f16* bdst[2];
#pragma unroll
    for (int j = 0; j < 2; ++j) {
        const int brow = wv * 32 + j * 16 + lrow4;
        const int bchunk = lslot ^ (((brow >> 2) ^ brow) & 3);
        bsrc[j] = Bt + ((size_t)e * NTOT + n0 + brow) * KB + kk0 + bchunk * 8;
        bdst[j] = Bs + (wv * 32 + j * 16) * 32;
    }

    f32x4 acc[4][4];
#pragma unroll
    for (int mi = 0; mi < 4; ++mi)
#pragma unroll
        for (int ni = 0; ni < 4; ++ni) acc[mi][ni] = f32x4{0.f, 0.f, 0.f, 0.f};

    for (int kt = 0; kt < NKT; ++kt) {
        const int ko = kt * 32;   // f16 units
        __syncthreads();          // prior iter's fragment reads complete
        gload_lds16(asrc + ko, adst);
        gload_lds16(bsrc[0] + ko, bdst[0]);
        gload_lds16(bsrc[1] + ko, bdst[1]);
        __syncthreads();          // loads landed (compiler drains vmcnt)
        {
            f16x8 af[4], bf[4];
            const int slot = lane >> 4;   // 0..3, k = slot*8..slot*8+8
#pragma unroll
            for (int mi = 0; mi < 4; ++mi) {
                const int row = wr * 64 + mi * 16 + (lane & 15);
                const int kb  = (slot ^ (((row >> 2) ^ row) & 3)) << 4;
                af[mi] = *(const f16x8*)((const char*)As + row * 64 + kb);
            }
#pragma unroll
            for (int ni = 0; ni < 4; ++ni) {
                const int n  = wc * 64 + ni * 16 + (lane & 15);
                const int kb = (slot ^ (((n >> 2) ^ n) & 3)) << 4;
                bf[ni] = *(const f16x8*)((const char*)Bs + n * 64 + kb);
            }
#pragma unroll
            for (int mi = 0; mi < 4; ++mi)
#pragma unroll
                for (int ni = 0; ni < 4; ++ni)
                    acc[mi][ni] = __builtin_amdgcn_mfma_f32_16x16x32_f16(
                        af[mi], bf[ni], acc[mi][ni], 0, 0, 0);
        }
    }

    // ---- epilogue: bare f16 partial store (r8-proven C/D mapping) ----
    constexpr int NOUT = FIRST ? HID : DIMC;
#pragma unroll
    for (int ni = 0; ni < 4; ++ni) {
        const int gc = n0 + wc * 64 + ni * 16 + (lane & 15);
#pragma unroll
        for (int mi = 0; mi < 4; ++mi) {
#pragma unroll
            for (int r = 0; r < 4; ++r) {
                const int lrow = wr * 64 + mi * 16 + (lane >> 4) * 4 + r;
                const int tok = rows[lrow];
                if (tok < 0) continue;
                Pout[((size_t)ks * T_TOKENS + tok) * NOUT + gc] =
                    (f16)acc[mi][ni][r];
            }
        }
    }
}

// ---------------------------------------------------------------------------
// H[t][c] = gelu(Hp0[t][c] + Hp1[t][c] + b1[eidx[t]][c])   [proven r12]
// ---------------------------------------------------------------------------
__global__ __launch_bounds__(256) void gelu_combine(
    const f16* __restrict__ Hp, const float* __restrict__ b1,
    const int* __restrict__ eidx, f16* __restrict__ H)
{
    const size_t i = ((size_t)blockIdx.x * 256 + threadIdx.x) * 8;
    const int t = (int)(i >> 12);          // / HID
    const int c = (int)(i & (HID - 1));
    const int e = eidx[t];
    const f16x8 a = *(const f16x8*)(Hp + i);
    const f16x8 b = *(const f16x8*)(Hp + (size_t)T_TOKENS * HID + i);
    const float4 ba = *(const float4*)(b1 + (size_t)e * HID + c);
    const float4 bb = *(const float4*)(b1 + (size_t)e * HID + c + 4);
    const float bj[8] = {ba.x, ba.y, ba.z, ba.w, bb.x, bb.y, bb.z, bb.w};
    f16x8 o;
#pragma unroll
    for (int j = 0; j < 8; ++j) {
        const float v = (float)a[j] + (float)b[j] + bj[j];
        o[j] = (f16)(0.5f * v * (1.f + erff(v * 0.70710678118f)));
    }
    *(f16x8*)(H + i) = o;
}

// ---------------------------------------------------------------------------
// out[t][c] = 2 * (sum_{ks<8} p8[ks][t][c]) + 2 * b2[eidx[t]][c]  [proven r13/14]
// ---------------------------------------------------------------------------
__global__ __launch_bounds__(256) void reduce8(
    const f16* __restrict__ p8, const float* __restrict__ b2,
    const int* __restrict__ eidx, float* __restrict__ out)
{
    constexpr size_t SL = (size_t)T_TOKENS * DIMC;
    const size_t i = ((size_t)blockIdx.x * 256 + threadIdx.x) * 8;
    const int t = (int)(i >> 10);          // / DIMC
    const int c = (int)(i & (DIMC - 1));
    const int e = eidx[t];
    float s[8] = {0.f, 0.f, 0.f, 0.f, 0.f, 0.f, 0.f, 0.f};
#pragma unroll
    for (int ks = 0; ks < 8; ++ks) {
        const f16x8 v = *(const f16x8*)(p8 + (size_t)ks * SL + i);
#pragma unroll
        for (int j = 0; j < 8; ++j) s[j] += (float)v[j];
    }
    const float4 ba = *(const float4*)(b2 + (size_t)e * DIMC + c);
    const float4 bb = *(const float4*)(b2 + (size_t)e * DIMC + c + 4);
    const float bj[8] = {ba.x, ba.y, ba.z, ba.w, bb.x, bb.y, bb.z, bb.w};
    float4 o0, o1;
    o0.x = 2.f * (s[0] + bj[0]); o0.y = 2.f * (s[1] + bj[1]);
    o0.z = 2.f * (s[2] + bj[2]); o0.w = 2.f * (s[3] + bj[3]);
    o1.x = 2.f * (s[4] + bj[4]); o1.y = 2.f * (s[5] + bj[5]);
    o1.z = 2.f * (s[6] + bj[6]); o1.w = 2.f * (s[7] + bj[7]);
    *(float4*)(out + i) = o0;
    *(float4*)(out + i + 4) = o1;
}

// ===========================================================================
// FALLBACK (round-3, proven) — used when ws_size < 233MB.
// ===========================================================================
template <bool FIRST>
__global__ __launch_bounds__(256) void ffn_gemm_fb(
    const float* __restrict__ x, const f16* __restrict__ Hin,
    const float* __restrict__ w1, const float* __restrict__ b1,
    const float* __restrict__ w2, const float* __restrict__ b2,
    const int* __restrict__ counts, const int* __restrict__ list,
    f16* __restrict__ Hout, float* __restrict__ out)
{
    constexpr int K = FIRST ? DIMC : HID;
    constexpr int N = FIRST ? HID : DIMC;
    constexpr int LDT = 40;

    const int e  = blockIdx.z;
    const int m0 = blockIdx.y * 128;
    const int n0 = blockIdx.x * 128;
    const int cnt = counts[e];
    if (m0 >= cnt) return;

    __shared__ f16 Ab[128 * LDT];
    __shared__ f16 Bb[128 * LDT];
    __shared__ int rows[128];

    const int tid = threadIdx.x;
    if (tid < 128) {
        const int p = m0 + tid;
        rows[tid] = (p < cnt) ? list[e * T_TOKENS + p] : -1;
    }
    __syncthreads();

    const int lane = tid & 63;
    const int wv = tid >> 6;
    const int wr = wv >> 1, wc = wv & 1;

    f32x4 acc[4][4];
#pragma unroll
    for (int mi = 0; mi < 4; ++mi)
#pragma unroll
        for (int ni = 0; ni < 4; ++ni) acc[mi][ni] = f32x4{0.f, 0.f, 0.f, 0.f};

    const float* Bsrc = (FIRST ? w1 : w2) + (size_t)e * K * N;

    for (int kk = 0; kk < K; kk += 32) {
        __syncthreads();
        {
            const int r  = tid >> 3;
            const int ko = (tid & 7) * 4;
#pragma unroll
            for (int p = 0; p < 4; ++p) {
                const int row = p * 32 + r;
                const int tok = rows[row];
                f16x4 hv;
                if (FIRST) {
                    float4 v;
                    if (tok >= 0) v = *(const float4*)(x + (size_t)tok * K + kk + ko);
                    else          v = make_float4(0.f, 0.f, 0.f, 0.f);
                    hv[0] = (f16)v.x; hv[1] = (f16)v.y; hv[2] = (f16)v.z; hv[3] = (f16)v.w;
                } else {
                    if (tok >= 0) hv = *(const f16x4*)(Hin + (size_t)tok * K + kk + ko);
                    else { hv[0] = (f16)0.f; hv[1] = (f16)0.f; hv[2] = (f16)0.f; hv[3] = (f16)0.f; }
                }
                *(f16x4*)&Ab[row * LDT + ko] = hv;
            }
        }
        {
            const int kb = tid >> 5;
            const int no = (tid & 31) * 4;
#pragma unroll
            for (int p = 0; p < 4; ++p) {
                const int k = p * 8 + kb;
                const float4 v = *(const float4*)(Bsrc + (size_t)(kk + k) * N + n0 + no);
                f16 h[4];
                h[0] = (f16)v.x; h[1] = (f16)v.y; h[2] = (f16)v.z; h[3] = (f16)v.w;
#pragma unroll
                for (int i = 0; i < 4; ++i) {
                    const int n = no + i;
                    const int chunk = (k >> 3) ^ ((n >> 2) & 3);
                    Bb[n * LDT + chunk * 8 + (k & 7)] = h[i];
                }
            }
        }
        __syncthreads();
        f16x8 af[4], bf[4];
#pragma unroll
        for (int mi = 0; mi < 4; ++mi) {
            const int row = wr * 64 + mi * 16 + (lane & 15);
            af[mi] = *(const f16x8*)&Ab[row * LDT + (lane >> 4) * 8];
        }
#pragma unroll
        for (int ni = 0; ni < 4; ++ni) {
            const int n = wc * 64 + ni * 16 + (lane & 15);
            const int chunk = (lane >> 4) ^ ((n >> 2) & 3);
            bf[ni] = *(const f16x8*)&Bb[n * LDT + chunk * 8];
        }
#pragma unroll
        for (int mi = 0; mi < 4; ++mi)
#pragma unroll
            for (int ni = 0; ni < 4; ++ni)
                acc[mi][ni] = __builtin_amdgcn_mfma_f32_16x16x32_f16(
                    af[mi], bf[ni], acc[mi][ni], 0, 0, 0);
    }

#pragma unroll
    for (int ni = 0; ni < 4; ++ni) {
        const int gc = n0 + wc * 64 + ni * 16 + (lane & 15);
        const float bias = FIRST ? b1[(size_t)e * HID + gc]
                                 : b2[(size_t)e * DIMC + gc];
#pragma unroll
        for (int mi = 0; mi < 4; ++mi) {
#pragma unroll
            for (int r = 0; r < 4; ++r) {
                const int lrow = wr * 64 + mi * 16 + (lane >> 4) * 4 + r;
                const int tok = rows[lrow];
                if (tok < 0) continue;
                const float v = acc[mi][ni][r] + bias;
                if (FIRST) {
                    const float g = 0.5f * v * (1.f + erff(v * 0.70710678118f));
                    Hout[(size_t)tok * HID + gc] = (f16)g;
                } else {
                    out[(size_t)tok * DIMC + gc] = 2.f * v;
                }
            }
        }
    }
}

// ---------------------------------------------------------------------------
extern "C" void kernel_launch(void* const* d_in, const int* in_sizes, int n_in,
                              void* d_out, int out_size, void* d_ws, size_t ws_size,
                              hipStream_t stream)
{
    const float* x   = (const float*)d_in[0];
    const float* gw  = (const float*)d_in[1];
    const float* gb  = (const float*)d_in[2];
    const float* w1  = (const float*)d_in[3];
    const float* b1  = (const float*)d_in[4];
    const float* w2  = (const float*)d_in[5];
    const float* b2  = (const float*)d_in[6];
    float* out = (float*)d_out;

    const size_t MB = 1 << 20;
    // layout: counts@0(1KB), list@1KB(128KB), eidx@512KB(16KB),
    //         xh@1MB(8MB), H@9MB(32MB), w1t@41MB(64MB), w2t@105MB(64MB),
    //         Hp/p8@169MB(64MB) -> 233MB
    const size_t need_p = 233 * MB;

    if (ws_size >= need_p) {
        int* counts = (int*)d_ws;
        int* list   = (int*)((char*)d_ws + 1024);
        int* eidx   = (int*)((char*)d_ws + 512 * 1024);
        f16* xh     = (f16*)((char*)d_ws + 1 * MB);
        f16* H      = (f16*)((char*)d_ws + 9 * MB);
        f16* w1t    = (f16*)((char*)d_ws + 41 * MB);
        f16* w2t    = (f16*)((char*)d_ws + 105 * MB);
        f16* Hp     = (f16*)((char*)d_ws + 169 * MB);
        f16* p8     = (f16*)((char*)d_ws + 169 * MB);

        hipMemsetAsync(counts, 0, 1024, stream);

        gating_kernel<<<T_TOKENS / 4, 256, 0, stream>>>(x, gw, gb, counts, list, eidx);
        xconvert<<<(T_TOKENS * DIMC) / (256 * 8), 256, 0, stream>>>(x, xh);
        wconvert<<<dim3(HID / 64, DIMC / 64, NE), 256, 0, stream>>>(w1, w1t, DIMC, HID);
        wconvert<<<dim3(DIMC / 64, HID / 64, NE), 256, 0, stream>>>(w2, w2t, HID, DIMC);

        // GEMM1: 128x256 BK=32, sk=2, bare f16 partials (1024 useful blocks)
        ffn_gemm9<true><<<dim3(HID / 256, T_TOKENS / 128, NE * 2), 512, 0, stream>>>(
            xh, w1t, counts, list, Hp);
        // H = gelu(Hp0+Hp1+b1[e])
        gelu_combine<<<(T_TOKENS * HID) / (256 * 8), 256, 0, stream>>>(Hp, b1, eidx, H);
        // GEMM2: 128x256 BK=32, sk=8, bare f16 partials (1024 useful blocks)
        ffn_gemm9<false><<<dim3(DIMC / 256, T_TOKENS / 128, NE * 8), 512, 0, stream>>>(
            H, w2t, counts, list, p8);
        // out = 2*(sum p8) + 2*b2[e]
        reduce8<<<(T_TOKENS * DIMC) / (256 * 8), 256, 0, stream>>>(p8, b2, eidx, out);
        return;
    }

    // ---- fallback (round-3 path, needs 33MB) ----
    const size_t need_fb = (size_t)(1 << 18) + (size_t)T_TOKENS * HID * sizeof(f16);
    if (ws_size < need_fb) return;

    int* counts = (int*)d_ws;
    int* list   = (int*)((char*)d_ws + 1024);
    int* eidx   = (int*)((char*)d_ws + 160 * 1024);
    f16* H      = (f16*)((char*)d_ws + (1 << 18));

    hipMemsetAsync(d_ws, 0, 1024, stream);
    gating_kernel<<<T_TOKENS / 4, 256, 0, stream>>>(x, gw, gb, counts, list, eidx);
    ffn_gemm_fb<true><<<dim3(HID / 128, T_TOKENS / 128, NE), 256, 0, stream>>>(
        x, (const f16*)nullptr, w1, b1, w2, b2, counts, list, H, out);
    ffn_gemm_fb<false><<<dim3(DIMC / 128, T_TOKENS / 128, NE), 256, 0, stream>>>(
        x, (const f16*)H, w1, b1, w2, b2, counts, list, H, out);
}

// Round 16
// 313.609 us; speedup vs baseline: 4.1824x; 1.0887x over previous
//
#include <hip/hip_runtime.h>
#include <hip/hip_bf16.h>
#include <hip/hip_fp16.h>

#define T_TOKENS 4096
#define DIMC 1024
#define HID 4096
#define NE 8

typedef _Float16 f16;
typedef _Float16 f16x8 __attribute__((ext_vector_type(8)));
typedef _Float16 f16x4 __attribute__((ext_vector_type(4)));
typedef float f32x4 __attribute__((ext_vector_type(4)));

__device__ __forceinline__ void gload_lds16(const f16* g, f16* l) {
    __builtin_amdgcn_global_load_lds(
        (const __attribute__((address_space(1))) void*)g,
        (__attribute__((address_space(3))) void*)l, 16, 0, 0);
}

// ---------------------------------------------------------------------------
// Proven bodies as device functions (verbatim logic from r12/r15).
// ---------------------------------------------------------------------------
__device__ __forceinline__ void gating_body(
    int bid, int tid, const float* __restrict__ x, const float* __restrict__ gw,
    const float* __restrict__ gb, int* __restrict__ counts,
    int* __restrict__ list, int* __restrict__ eidx)
{
    const int wave = tid >> 6;
    const int lane = tid & 63;
    const int t = bid * 4 + wave;

    const float* xr = x + (size_t)t * DIMC;
    float acc[NE];
#pragma unroll
    for (int e = 0; e < NE; ++e) acc[e] = 0.f;
    for (int i = 0; i < DIMC / 64; ++i) {
        const int k = i * 64 + lane;
        const float xv = xr[k];
        const float* g = gw + (size_t)k * NE;
#pragma unroll
        for (int e = 0; e < NE; ++e) acc[e] = fmaf(xv, g[e], acc[e]);
    }
#pragma unroll
    for (int off = 32; off >= 1; off >>= 1) {
#pragma unroll
        for (int e = 0; e < NE; ++e) acc[e] += __shfl_xor(acc[e], off, 64);
    }
    if (lane == 0) {
        float lg[NE];
#pragma unroll
        for (int e = 0; e < NE; ++e) lg[e] = acc[e] + gb[e];
        int i1 = 0; float v1 = lg[0];
#pragma unroll
        for (int e = 1; e < NE; ++e) { if (lg[e] > v1) { v1 = lg[e]; i1 = e; } }
        int i2 = -1; float v2 = -3.4e38f;
#pragma unroll
        for (int e = 0; e < NE; ++e) {
            if (e == i1) continue;
            if (lg[e] > v2) { v2 = lg[e]; i2 = e; }
        }
        const int es = (i1 > i2) ? i1 : i2;
        const int pos = atomicAdd(&counts[es], 1);
        list[es * T_TOKENS + pos] = t;
        eidx[t] = es;
    }
}

__device__ __forceinline__ void xconvert_body(
    int bid, int tid, const float* __restrict__ x, f16* __restrict__ xh)
{
    const size_t i = ((size_t)bid * 256 + tid) * 8;
    const float4 a = *(const float4*)(x + i);
    const float4 b = *(const float4*)(x + i + 4);
    f16x8 v;
    v[0] = (f16)a.x; v[1] = (f16)a.y; v[2] = (f16)a.z; v[3] = (f16)a.w;
    v[4] = (f16)b.x; v[5] = (f16)b.y; v[6] = (f16)b.z; v[7] = (f16)b.w;
    *(f16x8*)(xh + i) = v;
}

// 64x64 transpose-convert tile; block-wide barrier inside (callers keep the
// call uniform across the block).  Lt = per-caller LDS region, 64*72 f16.
__device__ __forceinline__ void wconv_tile(
    const float* __restrict__ W, f16* __restrict__ Wt, int K, int N,
    int bx, int by, int bz, int t, f16* Lt)
{
    const int n0 = bx * 64;
    const int k0 = by * 64;
    const float* Ws = W + (size_t)bz * K * N;
    const int no = (t & 15) * 4;
    const int kr = t >> 4;
#pragma unroll
    for (int p = 0; p < 4; ++p) {
        const int k = kr + p * 16;
        const float4 v = *(const float4*)(Ws + (size_t)(k0 + k) * N + n0 + no);
        Lt[(no + 0) * 72 + k] = (f16)v.x;
        Lt[(no + 1) * 72 + k] = (f16)v.y;
        Lt[(no + 2) * 72 + k] = (f16)v.z;
        Lt[(no + 3) * 72 + k] = (f16)v.w;
    }
    __syncthreads();
    const int n = t >> 2;
    const int ko = (t & 3) * 16;
    const f16x8 a = *(const f16x8*)&Lt[n * 72 + ko];
    const f16x8 b = *(const f16x8*)&Lt[n * 72 + ko + 8];
    f16* dst = Wt + ((size_t)bz * N + n0 + n) * K + k0 + ko;
    *(f16x8*)(dst) = a;
    *(f16x8*)(dst + 8) = b;
}

// ---------------------------------------------------------------------------
// PREP: gating (1024 blocks) || xconvert (2048) || wconvert-w1 (8192 tiles).
// 256 threads.  Branches are block-uniform; only wconv branch has a barrier.
// ---------------------------------------------------------------------------
__global__ __launch_bounds__(256) void prep_kernel(
    const float* __restrict__ x, const float* __restrict__ gw,
    const float* __restrict__ gb, const float* __restrict__ w1,
    int* __restrict__ counts, int* __restrict__ list, int* __restrict__ eidx,
    f16* __restrict__ xh, f16* __restrict__ w1t)
{
    __shared__ f16 Lt[64 * 72];
    const int bid = blockIdx.x;
    const int tid = threadIdx.x;
    if (bid < 1024) {
        gating_body(bid, tid, x, gw, gb, counts, list, eidx);
    } else if (bid < 1024 + 2048) {
        xconvert_body(bid - 1024, tid, x, xh);
    } else {
        const int t2 = bid - 3072;            // [0, 8192): w1 [e][1024][4096]
        const int bx = t2 & 63;               // over N=HID (64 tiles)
        const int by = (t2 >> 6) & 15;        // over K=DIMC (16 tiles)
        const int bz = t2 >> 10;              // expert
        wconv_tile(w1, w1t, DIMC, HID, bx, by, bz, tid, Lt);
    }
}

// ---------------------------------------------------------------------------
// GEMM1 (r15-proven 128m x 256n BK=32 body) FUSED with wconvert-w2.
// grid dim3(16, 32, 24), 512 threads:
//   z in [0,16):  G1, e=z>>1, ks=z&1  -> bare f16 Hp[ks]
//   z in [16,24): wc2 slots; each 512-thr block = 2 independent 256-thr
//                 wconvert tiles of w2 (halves h=tid>>8).
// ---------------------------------------------------------------------------
__global__ __launch_bounds__(512) void gemm1_wc2(
    const f16* __restrict__ A, const f16* __restrict__ Bt,
    const float* __restrict__ w2, f16* __restrict__ w2t,
    const int* __restrict__ counts, const int* __restrict__ list,
    f16* __restrict__ Pout)
{
    __shared__ __align__(16) char smem[25088];
    const int tid = threadIdx.x;
    const int zz  = blockIdx.z;

    if (zz >= 16) {
        // ---- wconvert(w2): K=HID, N=DIMC; tiles 16 x 64 x 8 = 8192 ----
        const int s = blockIdx.x + blockIdx.y * 16 + (zz - 16) * 512;  // [0,4096)
        const int h = tid >> 8;               // half 0/1
        const int t = s * 2 + h;              // tile id [0, 8192)
        const int bx = t & 15;                // over N=DIMC
        const int by = (t >> 4) & 63;         // over K=HID
        const int bz = t >> 10;               // expert
        f16* Lt = (f16*)smem + h * (64 * 72);
        wconv_tile(w2, w2t, HID, DIMC, bx, by, bz, tid & 255, Lt);
        return;
    }

    // ---- G1 body: r15-proven ffn_gemm9<true> verbatim ----
    constexpr int KB   = DIMC;
    constexpr int NTOT = HID;
    constexpr int NKT  = 16;

    const int e   = zz >> 1;
    const int ks  = zz & 1;
    const int kk0 = ks * 512;
    const int m0  = blockIdx.y * 128;
    const int n0  = blockIdx.x * 256;
    const int cnt = counts[e];
    if (m0 >= cnt) return;

    f16* As = (f16*)smem;                     //  8 KB  [128][32]
    f16* Bs = (f16*)(smem + 8192);            // 16 KB  [256][32]
    int* rows = (int*)(smem + 8192 + 16384);  // 512 B

    if (tid < 128) rows[tid] = (m0 + tid < cnt) ? list[e * T_TOKENS + m0 + tid] : -1;
    __syncthreads();

    const int lane = tid & 63;
    const int wv   = tid >> 6;      // 0..7
    const int wr   = wv >> 2;       // 0..1
    const int wc   = wv & 3;        // 0..3

    const int lrow4 = lane >> 2;
    const int lslot = lane & 3;

    const int arow = wv * 16 + lrow4;
    int tokA = rows[arow]; if (tokA < 0) tokA = 0;
    const int achunk = lslot ^ (((arow >> 2) ^ arow) & 3);
    const f16* asrc = A + (size_t)tokA * KB + kk0 + achunk * 8;
    f16* adst = As + (wv * 16) * 32;

    const f16* bsrc[2];
    f16* bdst[2];
#pragma unroll
    for (int j = 0; j < 2; ++j) {
        const int brow = wv * 32 + j * 16 + lrow4;
        const int bchunk = lslot ^ (((brow >> 2) ^ brow) & 3);
        bsrc[j] = Bt + ((size_t)e * NTOT + n0 + brow) * KB + kk0 + bchunk * 8;
        bdst[j] = Bs + (wv * 32 + j * 16) * 32;
    }

    f32x4 acc[4][4];
#pragma unroll
    for (int mi = 0; mi < 4; ++mi)
#pragma unroll
        for (int ni = 0; ni < 4; ++ni) acc[mi][ni] = f32x4{0.f, 0.f, 0.f, 0.f};

    for (int kt = 0; kt < NKT; ++kt) {
        const int ko = kt * 32;
        __syncthreads();
        gload_lds16(asrc + ko, adst);
        gload_lds16(bsrc[0] + ko, bdst[0]);
        gload_lds16(bsrc[1] + ko, bdst[1]);
        __syncthreads();
        {
            f16x8 af[4], bf[4];
            const int slot = lane >> 4;
#pragma unroll
            for (int mi = 0; mi < 4; ++mi) {
                const int row = wr * 64 + mi * 16 + (lane & 15);
                const int kb  = (slot ^ (((row >> 2) ^ row) & 3)) << 4;
                af[mi] = *(const f16x8*)((const char*)As + row * 64 + kb);
            }
#pragma unroll
            for (int ni = 0; ni < 4; ++ni) {
                const int n  = wc * 64 + ni * 16 + (lane & 15);
                const int kb = (slot ^ (((n >> 2) ^ n) & 3)) << 4;
                bf[ni] = *(const f16x8*)((const char*)Bs + n * 64 + kb);
            }
#pragma unroll
            for (int mi = 0; mi < 4; ++mi)
#pragma unroll
                for (int ni = 0; ni < 4; ++ni)
                    acc[mi][ni] = __builtin_amdgcn_mfma_f32_16x16x32_f16(
                        af[mi], bf[ni], acc[mi][ni], 0, 0, 0);
        }
    }

#pragma unroll
    for (int ni = 0; ni < 4; ++ni) {
        const int gc = n0 + wc * 64 + ni * 16 + (lane & 15);
#pragma unroll
        for (int mi = 0; mi < 4; ++mi) {
#pragma unroll
            for (int r = 0; r < 4; ++r) {
                const int lrow = wr * 64 + mi * 16 + (lane >> 4) * 4 + r;
                const int tok = rows[lrow];
                if (tok < 0) continue;
                Pout[((size_t)ks * T_TOKENS + tok) * HID + gc] =
                    (f16)acc[mi][ni][r];
            }
        }
    }
}

// ---------------------------------------------------------------------------
// GEMM2: r15-proven ffn_gemm9<false> (128m x 256n, BK=32, sk=8).
// ---------------------------------------------------------------------------
__global__ __launch_bounds__(512) void ffn_gemm9b(
    const f16* __restrict__ A, const f16* __restrict__ Bt,
    const int* __restrict__ counts, const int* __restrict__ list,
    f16* __restrict__ Pout)
{
    constexpr int KB   = HID;
    constexpr int NTOT = DIMC;
    constexpr int NKT  = 16;

    const int zz  = blockIdx.z;
    const int e   = zz >> 3;
    const int ks  = zz & 7;
    const int kk0 = ks * 512;
    const int m0  = blockIdx.y * 128;
    const int n0  = blockIdx.x * 256;
    const int cnt = counts[e];
    if (m0 >= cnt) return;

    __shared__ __align__(16) f16 As[128 * 32];
    __shared__ __align__(16) f16 Bs[256 * 32];
    __shared__ int rows[128];

    const int tid = threadIdx.x;
    if (tid < 128) rows[tid] = (m0 + tid < cnt) ? list[e * T_TOKENS + m0 + tid] : -1;
    __syncthreads();

    const int lane = tid & 63;
    const int wv   = tid >> 6;
    const int wr   = wv >> 2;
    const int wc   = wv & 3;

    const int lrow4 = lane >> 2;
    const int lslot = lane & 3;

    const int arow = wv * 16 + lrow4;
    int tokA = rows[arow]; if (tokA < 0) tokA = 0;
    const int achunk = lslot ^ (((arow >> 2) ^ arow) & 3);
    const f16* asrc = A + (size_t)tokA * KB + kk0 + achunk * 8;
    f16* adst = As + (wv * 16) * 32;

    const f16* bsrc[2];
    f16* bdst[2];
#pragma unroll
    for (int j = 0; j < 2; ++j) {
        const int brow = wv * 32 + j * 16 + lrow4;
        const int bchunk = lslot ^ (((brow >> 2) ^ brow) & 3);
        bsrc[j] = Bt + ((size_t)e * NTOT + n0 + brow) * KB + kk0 + bchunk * 8;
        bdst[j] = Bs + (wv * 32 + j * 16) * 32;
    }

    f32x4 acc[4][4];
#pragma unroll
    for (int mi = 0; mi < 4; ++mi)
#pragma unroll
        for (int ni = 0; ni < 4; ++ni) acc[mi][ni] = f32x4{0.f, 0.f, 0.f, 0.f};

    for (int kt = 0; kt < NKT; ++kt) {
        const int ko = kt * 32;
        __syncthreads();
        gload_lds16(asrc + ko, adst);
        gload_lds16(bsrc[0] + ko, bdst[0]);
        gload_lds16(bsrc[1] + ko, bdst[1]);
        __syncthreads();
        {
            f16x8 af[4], bf[4];
            const int slot = lane >> 4;
#pragma unroll
            for (int mi = 0; mi < 4; ++mi) {
                const int row = wr * 64 + mi * 16 + (lane & 15);
                const int kb  = (slot ^ (((row >> 2) ^ row) & 3)) << 4;
                af[mi] = *(const f16x8*)((const char*)As + row * 64 + kb);
            }
#pragma unroll
            for (int ni = 0; ni < 4; ++ni) {
                const int n  = wc * 64 + ni * 16 + (lane & 15);
                const int kb = (slot ^ (((n >> 2) ^ n) & 3)) << 4;
                bf[ni] = *(const f16x8*)((const char*)Bs + n * 64 + kb);
            }
#pragma unroll
            for (int mi = 0; mi < 4; ++mi)
#pragma unroll
                for (int ni = 0; ni < 4; ++ni)
                    acc[mi][ni] = __builtin_amdgcn_mfma_f32_16x16x32_f16(
                        af[mi], bf[ni], acc[mi][ni], 0, 0, 0);
        }
    }

#pragma unroll
    for (int ni = 0; ni < 4; ++ni) {
        const int gc = n0 + wc * 64 + ni * 16 + (lane & 15);
#pragma unroll
        for (int mi = 0; mi < 4; ++mi) {
#pragma unroll
            for (int r = 0; r < 4; ++r) {
                const int lrow = wr * 64 + mi * 16 + (lane >> 4) * 4 + r;
                const int tok = rows[lrow];
                if (tok < 0) continue;
                Pout[((size_t)ks * T_TOKENS + tok) * DIMC + gc] =
                    (f16)acc[mi][ni][r];
            }
        }
    }
}

// ---------------------------------------------------------------------------
// H[t][c] = gelu(Hp0 + Hp1 + b1[eidx[t]][c])   [proven r12]
// ---------------------------------------------------------------------------
__global__ __launch_bounds__(256) void gelu_combine(
    const f16* __restrict__ Hp, const float* __restrict__ b1,
    const int* __restrict__ eidx, f16* __restrict__ H)
{
    const size_t i = ((size_t)blockIdx.x * 256 + threadIdx.x) * 8;
    const int t = (int)(i >> 12);
    const int c = (int)(i & (HID - 1));
    const int e = eidx[t];
    const f16x8 a = *(const f16x8*)(Hp + i);
    const f16x8 b = *(const f16x8*)(Hp + (size_t)T_TOKENS * HID + i);
    const float4 ba = *(const float4*)(b1 + (size_t)e * HID + c);
    const float4 bb = *(const float4*)(b1 + (size_t)e * HID + c + 4);
    const float bj[8] = {ba.x, ba.y, ba.z, ba.w, bb.x, bb.y, bb.z, bb.w};
    f16x8 o;
#pragma unroll
    for (int j = 0; j < 8; ++j) {
        const float v = (float)a[j] + (float)b[j] + bj[j];
        o[j] = (f16)(0.5f * v * (1.f + erff(v * 0.70710678118f)));
    }
    *(f16x8*)(H + i) = o;
}

// ---------------------------------------------------------------------------
// out = 2*(sum_{ks<8} p8[ks]) + 2*b2[eidx[t]]   [proven r13/r14/r15]
// ---------------------------------------------------------------------------
__global__ __launch_bounds__(256) void reduce8(
    const f16* __restrict__ p8, const float* __restrict__ b2,
    const int* __restrict__ eidx, float* __restrict__ out)
{
    constexpr size_t SL = (size_t)T_TOKENS * DIMC;
    const size_t i = ((size_t)blockIdx.x * 256 + threadIdx.x) * 8;
    const int t = (int)(i >> 10);
    const int c = (int)(i & (DIMC - 1));
    const int e = eidx[t];
    float s[8] = {0.f, 0.f, 0.f, 0.f, 0.f, 0.f, 0.f, 0.f};
#pragma unroll
    for (int ks = 0; ks < 8; ++ks) {
        const f16x8 v = *(const f16x8*)(p8 + (size_t)ks * SL + i);
#pragma unroll
        for (int j = 0; j < 8; ++j) s[j] += (float)v[j];
    }
    const float4 ba = *(const float4*)(b2 + (size_t)e * DIMC + c);
    const float4 bb = *(const float4*)(b2 + (size_t)e * DIMC + c + 4);
    const float bj[8] = {ba.x, ba.y, ba.z, ba.w, bb.x, bb.y, bb.z, bb.w};
    float4 o0, o1;
    o0.x = 2.f * (s[0] + bj[0]); o0.y = 2.f * (s[1] + bj[1]);
    o0.z = 2.f * (s[2] + bj[2]); o0.w = 2.f * (s[3] + bj[3]);
    o1.x = 2.f * (s[4] + bj[4]); o1.y = 2.f * (s[5] + bj[5]);
    o1.z = 2.f * (s[6] + bj[6]); o1.w = 2.f * (s[7] + bj[7]);
    *(float4*)(out + i) = o0;
    *(float4*)(out + i + 4) = o1;
}

// ===========================================================================
// FALLBACK (round-3, proven) — used when ws_size < 233MB.
// ===========================================================================
template <bool FIRST>
__global__ __launch_bounds__(256) void ffn_gemm_fb(
    const float* __restrict__ x, const f16* __restrict__ Hin,
    const float* __restrict__ w1, const float* __restrict__ b1,
    const float* __restrict__ w2, const float* __restrict__ b2,
    const int* __restrict__ counts, const int* __restrict__ list,
    f16* __restrict__ Hout, float* __restrict__ out)
{
    constexpr int K = FIRST ? DIMC : HID;
    constexpr int N = FIRST ? HID : DIMC;
    constexpr int LDT = 40;

    const int e  = blockIdx.z;
    const int m0 = blockIdx.y * 128;
    const int n0 = blockIdx.x * 128;
    const int cnt = counts[e];
    if (m0 >= cnt) return;

    __shared__ f16 Ab[128 * LDT];
    __shared__ f16 Bb[128 * LDT];
    __shared__ int rows[128];

    const int tid = threadIdx.x;
    if (tid < 128) {
        const int p = m0 + tid;
        rows[tid] = (p < cnt) ? list[e * T_TOKENS + p] : -1;
    }
    __syncthreads();

    const int lane = tid & 63;
    const int wv = tid >> 6;
    const int wr = wv >> 1, wc = wv & 1;

    f32x4 acc[4][4];
#pragma unroll
    for (int mi = 0; mi < 4; ++mi)
#pragma unroll
        for (int ni = 0; ni < 4; ++ni) acc[mi][ni] = f32x4{0.f, 0.f, 0.f, 0.f};

    const float* Bsrc = (FIRST ? w1 : w2) + (size_t)e * K * N;

    for (int kk = 0; kk < K; kk += 32) {
        __syncthreads();
        {
            const int r  = tid >> 3;
            const int ko = (tid & 7) * 4;
#pragma unroll
            for (int p = 0; p < 4; ++p) {
                const int row = p * 32 + r;
                const int tok = rows[row];
                f16x4 hv;
                if (FIRST) {
                    float4 v;
                    if (tok >= 0) v = *(const float4*)(x + (size_t)tok * K + kk + ko);
                    else          v = make_float4(0.f, 0.f, 0.f, 0.f);
                    hv[0] = (f16)v.x; hv[1] = (f16)v.y; hv[2] = (f16)v.z; hv[3] = (f16)v.w;
                } else {
                    if (tok >= 0) hv = *(const f16x4*)(Hin + (size_t)tok * K + kk + ko);
                    else { hv[0] = (f16)0.f; hv[1] = (f16)0.f; hv[2] = (f16)0.f; hv[3] = (f16)0.f; }
                }
                *(f16x4*)&Ab[row * LDT + ko] = hv;
            }
        }
        {
            const int kb = tid >> 5;
            const int no = (tid & 31) * 4;
#pragma unroll
            for (int p = 0; p < 4; ++p) {
                const int k = p * 8 + kb;
                const float4 v = *(const float4*)(Bsrc + (size_t)(kk + k) * N + n0 + no);
                f16 h[4];
                h[0] = (f16)v.x; h[1] = (f16)v.y; h[2] = (f16)v.z; h[3] = (f16)v.w;
#pragma unroll
                for (int i = 0; i < 4; ++i) {
                    const int n = no + i;
                    const int chunk = (k >> 3) ^ ((n >> 2) & 3);
                    Bb[n * LDT + chunk * 8 + (k & 7)] = h[i];
                }
            }
        }
        __syncthreads();
        f16x8 af[4], bf[4];
#pragma unroll
        for (int mi = 0; mi < 4; ++mi) {
            const int row = wr * 64 + mi * 16 + (lane & 15);
            af[mi] = *(const f16x8*)&Ab[row * LDT + (lane >> 4) * 8];
        }
#pragma unroll
        for (int ni = 0; ni < 4; ++ni) {
            const int n = wc * 64 + ni * 16 + (lane & 15);
            const int chunk = (lane >> 4) ^ ((n >> 2) & 3);
            bf[ni] = *(const f16x8*)&Bb[n * LDT + chunk * 8];
        }
#pragma unroll
        for (int mi = 0; mi < 4; ++mi)
#pragma unroll
            for (int ni = 0; ni < 4; ++ni)
                acc[mi][ni] = __builtin_amdgcn_mfma_f32_16x16x32_f16(
                    af[mi], bf[ni], acc[mi][ni], 0, 0, 0);
    }

#pragma unroll
    for (int ni = 0; ni < 4; ++ni) {
        const int gc = n0 + wc * 64 + ni * 16 + (lane & 15);
        const float bias = FIRST ? b1[(size_t)e * HID + gc]
                                 : b2[(size_t)e * DIMC + gc];
#pragma unroll
        for (int mi = 0; mi < 4; ++mi) {
#pragma unroll
            for (int r = 0; r < 4; ++r) {
                const int lrow = wr * 64 + mi * 16 + (lane >> 4) * 4 + r;
                const int tok = rows[lrow];
                if (tok < 0) continue;
                const float v = acc[mi][ni][r] + bias;
                if (FIRST) {
                    const float g = 0.5f * v * (1.f + erff(v * 0.70710678118f));
                    Hout[(size_t)tok * HID + gc] = (f16)g;
                } else {
                    out[(size_t)tok * DIMC + gc] = 2.f * v;
                }
            }
        }
    }
}

__global__ __launch_bounds__(256) void gating_fb(
    const float* __restrict__ x, const float* __restrict__ gw,
    const float* __restrict__ gb, int* __restrict__ counts,
    int* __restrict__ list, int* __restrict__ eidx)
{
    gating_body(blockIdx.x, threadIdx.x, x, gw, gb, counts, list, eidx);
}

// ---------------------------------------------------------------------------
extern "C" void kernel_launch(void* const* d_in, const int* in_sizes, int n_in,
                              void* d_out, int out_size, void* d_ws, size_t ws_size,
                              hipStream_t stream)
{
    const float* x   = (const float*)d_in[0];
    const float* gw  = (const float*)d_in[1];
    const float* gb  = (const float*)d_in[2];
    const float* w1  = (const float*)d_in[3];
    const float* b1  = (const float*)d_in[4];
    const float* w2  = (const float*)d_in[5];
    const float* b2  = (const float*)d_in[6];
    float* out = (float*)d_out;

    const size_t MB = 1 << 20;
    // layout: counts@0(1KB), list@1KB(128KB), eidx@512KB(16KB),
    //         xh@1MB(8MB), H@9MB(32MB), w1t@41MB(64MB), w2t@105MB(64MB),
    //         Hp/p8@169MB(64MB) -> 233MB
    const size_t need_p = 233 * MB;

    if (ws_size >= need_p) {
        int* counts = (int*)d_ws;
        int* list   = (int*)((char*)d_ws + 1024);
        int* eidx   = (int*)((char*)d_ws + 512 * 1024);
        f16* xh     = (f16*)((char*)d_ws + 1 * MB);
        f16* H      = (f16*)((char*)d_ws + 9 * MB);
        f16* w1t    = (f16*)((char*)d_ws + 41 * MB);
        f16* w2t    = (f16*)((char*)d_ws + 105 * MB);
        f16* Hp     = (f16*)((char*)d_ws + 169 * MB);
        f16* p8     = (f16*)((char*)d_ws + 169 * MB);

        hipMemsetAsync(counts, 0, 1024, stream);

        // prep: gating || xconvert || wconvert(w1)
        prep_kernel<<<1024 + 2048 + 8192, 256, 0, stream>>>(
            x, gw, gb, w1, counts, list, eidx, xh, w1t);

        // GEMM1 (r15 body) fused with wconvert(w2)
        gemm1_wc2<<<dim3(16, 32, 24), 512, 0, stream>>>(
            xh, w1t, w2, w2t, counts, list, Hp);

        // H = gelu(Hp0+Hp1+b1[e])
        gelu_combine<<<(T_TOKENS * HID) / (256 * 8), 256, 0, stream>>>(Hp, b1, eidx, H);

        // GEMM2 (r15 body), sk=8, bare f16 partials
        ffn_gemm9b<<<dim3(DIMC / 256, T_TOKENS / 128, NE * 8), 512, 0, stream>>>(
            H, w2t, counts, list, p8);

        // out = 2*(sum p8) + 2*b2[e]
        reduce8<<<(T_TOKENS * DIMC) / (256 * 8), 256, 0, stream>>>(p8, b2, eidx, out);
        return;
    }

    // ---- fallback (round-3 path, needs 33MB) ----
    const size_t need_fb = (size_t)(1 << 18) + (size_t)T_TOKENS * HID * sizeof(f16);
    if (ws_size < need_fb) return;

    int* counts = (int*)d_ws;
    int* list   = (int*)((char*)d_ws + 1024);
    int* eidx   = (int*)((char*)d_ws + 160 * 1024);
    f16* H      = (f16*)((char*)d_ws + (1 << 18));

    hipMemsetAsync(d_ws, 0, 1024, stream);
    gating_fb<<<T_TOKENS / 4, 256, 0, stream>>>(x, gw, gb, counts, list, eidx);
    ffn_gemm_fb<true><<<dim3(HID / 128, T_TOKENS / 128, NE), 256, 0, stream>>>(
        x, (const f16*)nullptr, w1, b1, w2, b2, counts, list, H, out);
    ffn_gemm_fb<false><<<dim3(DIMC / 128, T_TOKENS / 128, NE), 256, 0, stream>>>(
        x, (const f16*)H, w1, b1, w2, b2, counts, list, H, out);
}